// Round 1
// baseline (145.917 us; speedup 1.0000x reference)
//
#include <hip/hip_runtime.h>

#define KK 4096
#define NN 11008
#define NGRP 32
#define KW 2048             // int32 words per qweight row
#define WS_RS_OFF 131072    // ws: [0,128K) A_perm bf16; [128K,+2K) rowsum

using short8  = __attribute__((ext_vector_type(8))) short;
using float4v = __attribute__((ext_vector_type(4))) float;

static __device__ __forceinline__ unsigned int pack_bf16(float lo, float hi) {
    unsigned int ul = __builtin_bit_cast(unsigned int, lo);
    unsigned int uh = __builtin_bit_cast(unsigned int, hi);
    ul = (ul + 0x7FFFu + ((ul >> 16) & 1u)) >> 16;
    uh = (uh + 0x7FFFu + ((uh >> 16) & 1u)) & 0xFFFF0000u;
    return ul | uh;
}
static __device__ __forceinline__ float bf16val(float f) {
    unsigned int u = __builtin_bit_cast(unsigned int, f);
    u = (u + 0x7FFFu + ((u >> 16) & 1u)) & 0xFFFF0000u;
    return __builtin_bit_cast(float, u);
}

// prep: b<32  -> A_perm: fragment-linear bf16 A. Chunk c = k/32 occupies
//                shorts [c*512, +512); lane l holds A[l&15][c*32+(l>>4)*8..+8].
//       32-63 -> per-(m,group) row sums of bf16(A).
// (R9: SZ branch removed — correction now computed in qgemm's epilogue.)
__global__ __launch_bounds__(256) void prep_kernel(
    const float* __restrict__ A, unsigned short* __restrict__ wsA,
    float* __restrict__ rowsum)
{
    const int b = blockIdx.x, t = threadIdx.x;
    if (b < 32) {
        const int tid = b * 256 + t;          // 0..8191 = (chunk c)*64 + lane
        const int c = tid >> 6, l = tid & 63;
        const float* src = A + (size_t)(l & 15) * KK + c * 32 + (l >> 4) * 8;
        float4v x0 = *(const float4v*)src;
        float4v x1 = *(const float4v*)(src + 4);
        union { short8 s8; unsigned int u[4]; } p;
        p.u[0] = pack_bf16(x0[0], x0[1]);
        p.u[1] = pack_bf16(x0[2], x0[3]);
        p.u[2] = pack_bf16(x1[0], x1[1]);
        p.u[3] = pack_bf16(x1[2], x1[3]);
        *(short8*)(wsA + (size_t)tid * 8) = p.s8;
    } else {
        const int sid = (b - 32) * 16 + (t >> 4);   // m*32+g
        const int m = sid >> 5, g = sid & 31, j = t & 15;
        const float* p = A + (size_t)m * KK + g * 128 + j * 8;
        float4v x0 = *(const float4v*)p;
        float4v x1 = *(const float4v*)(p + 4);
        float sum = bf16val(x0[0]) + bf16val(x0[1]) + bf16val(x0[2]) + bf16val(x0[3])
                  + bf16val(x1[0]) + bf16val(x1[1]) + bf16val(x1[2]) + bf16val(x1[3]);
        sum += __shfl_xor(sum, 1, 16);
        sum += __shfl_xor(sum, 2, 16);
        sum += __shfl_xor(sum, 4, 16);
        sum += __shfl_xor(sum, 8, 16);
        if (j == 0) rowsum[sid] = sum;
    }
}

// R9 hot kernel: 688 blocks = one 16-col n-tile each, FULL K per block.
// 8 waves/block, wave w owns groups w*4..w*4+3. All 16 qweight int4 loads
// issued up front (16 KB in flight/CU at 16 waves/CU -> ~4.6 TB/s effective
// vs 2.3 TB/s with the old 4-in-flight structure). A-fragments double-
// buffered 2 groups deep (L2-hot, ~200cy). Single barrier (R7: no barrier in
// the load->MFMA path). No atomics, no init_out: bias - sum_g s*(128+z)*rowsum
// folded into the epilogue after the 8-wave LDS reduce.
__global__ __launch_bounds__(512, 4) void qgemm_kernel(
    const int*            __restrict__ qweight,  // (11008, 2048) words
    const float*          __restrict__ scales,   // (11008, 32)
    const float*          __restrict__ zeros,    // (11008, 32)
    const float*          __restrict__ bias,     // (11008)
    const unsigned short* __restrict__ aperm,    // fragment-linear bf16 A
    const float*          __restrict__ rowsum,   // (16, 32)
    float*                __restrict__ out)      // (16, 11008) fp32
{
    __shared__ float red[8][16][16];   // per-wave partials
    __shared__ float szs[32][17];      // s*(128+z), padded (write was 16-way)
    __shared__ float rss[16][33];      // rowsum, padded for epilogue reads

    const int t = threadIdx.x;
    const int n0 = blockIdx.x * 16;
    const int wid = t >> 6, lane = t & 63;
    const int nl = lane & 15, quad = lane >> 4;
    const int n = n0 + nl;
    const int g0 = wid * 4;                       // first of this wave's 4 groups

    const int* qrow = qweight + (size_t)n * KW + g0 * 64 + quad * 4;
    const unsigned short* ap = aperm + (size_t)g0 * 2048 + (size_t)lane * 8;

    // ---- epilogue staging: 3 small loads, issued first (oldest in queue) ----
    const int sg = t & 31, sn = t >> 5;           // t = sn*32+sg
    const float sv = scales[(size_t)(n0 + sn) * NGRP + sg];
    const float zv = zeros[(size_t)(n0 + sn) * NGRP + sg];
    const float rv = rowsum[t];

    // ---- the latency-hiding core: all 16 qweight loads in flight ----
    int4 qw[4][4];
    #pragma unroll
    for (int j = 0; j < 4; ++j)
        #pragma unroll
        for (int c = 0; c < 4; ++c)
            qw[j][c] = *(const int4*)(qrow + j * 64 + c * 16);

    float sj[4];
    #pragma unroll
    for (int j = 0; j < 4; ++j)
        sj[j] = scales[(size_t)n * NGRP + g0 + j];

    // A fragments: 2 groups deep
    short8 apA[4], apB[4];
    #pragma unroll
    for (int c = 0; c < 4; ++c) apA[c] = *(const short8*)(ap + c * 512);
    #pragma unroll
    for (int c = 0; c < 4; ++c) apB[c] = *(const short8*)(ap + 2048 + c * 512);

    // park staging values in LDS (consumed only after the barrier)
    szs[sg][sn] = sv * (128.0f + zv);
    rss[t >> 5][t & 31] = rv;

    float4v tot = {0.f, 0.f, 0.f, 0.f};

#define DEQ_MFMA(J, APV)                                                      \
    {                                                                         \
        float4v accg = {0.f, 0.f, 0.f, 0.f};                                  \
        _Pragma("unroll")                                                     \
        for (int c = 0; c < 4; ++c) {                                         \
            const unsigned int x0 = (unsigned int)qw[J][c].x;                 \
            const unsigned int x1 = (unsigned int)qw[J][c].y;                 \
            const unsigned int x2 = (unsigned int)qw[J][c].z;                 \
            const unsigned int x3 = (unsigned int)qw[J][c].w;                 \
            union { short8 s8; unsigned int u[4]; } bf;  /* bf16(128+q) */    \
            bf.u[0] = (x0 & 0xFu) | ((x0 << 12) & 0x000F0000u) | 0x43004300u; \
            bf.u[1] = (x1 & 0xFu) | ((x1 << 12) & 0x000F0000u) | 0x43004300u; \
            bf.u[2] = (x2 & 0xFu) | ((x2 << 12) & 0x000F0000u) | 0x43004300u; \
            bf.u[3] = (x3 & 0xFu) | ((x3 << 12) & 0x000F0000u) | 0x43004300u; \
            accg = __builtin_amdgcn_mfma_f32_16x16x32_bf16(APV[c], bf.s8,     \
                                                           accg, 0, 0, 0);    \
        }                                                                     \
        _Pragma("unroll")                                                     \
        for (int r = 0; r < 4; ++r) tot[r] += sj[J] * accg[r];                \
    }

    DEQ_MFMA(0, apA)
    #pragma unroll
    for (int c = 0; c < 4; ++c) apA[c] = *(const short8*)(ap + 2 * 2048 + c * 512);
    DEQ_MFMA(1, apB)
    #pragma unroll
    for (int c = 0; c < 4; ++c) apB[c] = *(const short8*)(ap + 3 * 2048 + c * 512);
    DEQ_MFMA(2, apA)
    DEQ_MFMA(3, apB)
#undef DEQ_MFMA

    // C/D mapping: m = quad*4+r, n = nl  [m89]
    #pragma unroll
    for (int r = 0; r < 4; ++r)
        red[wid][quad * 4 + r][nl] = tot[r];
    __syncthreads();   // the ONLY barrier

    if (t < 256) {
        const int m = t >> 4, nn = t & 15;
        float v = 0.f;
        #pragma unroll
        for (int w = 0; w < 8; ++w) v += red[w][m][nn];
        float corr = 0.f;
        #pragma unroll
        for (int g = 0; g < 32; ++g)
            corr = __builtin_fmaf(szs[g][nn], rss[m][g], corr);
        out[(size_t)m * NN + n0 + nn] = bias[n0 + nn] + v - corr;
    }
}

extern "C" void kernel_launch(void* const* d_in, const int* in_sizes, int n_in,
                              void* d_out, int out_size, void* d_ws, size_t ws_size,
                              hipStream_t stream) {
    const float* A       = (const float*)d_in[0];
    const int*   qweight = (const int*)d_in[1];
    const float* scales  = (const float*)d_in[2];
    const float* zeros   = (const float*)d_in[3];
    const float* bias    = (const float*)d_in[4];
    float*       out     = (float*)d_out;

    unsigned short* wsA = (unsigned short*)d_ws;
    float* rowsum       = (float*)((char*)d_ws + WS_RS_OFF);

    prep_kernel<<<dim3(64), dim3(256), 0, stream>>>(A, wsA, rowsum);
    qgemm_kernel<<<dim3(688), dim3(512), 0, stream>>>(qweight, scales, zeros, bias,
                                                      wsA, rowsum, out);
}

// Round 2
// 145.712 us; speedup vs baseline: 1.0014x; 1.0014x over previous
//
#include <hip/hip_runtime.h>

#define KK 4096
#define NN 11008
#define NGRP 32
#define KW 2048             // int32 words per qweight row (1 byte / 2 nibbles per word)
#define WS_RS_OFF 131072    // ws: [0,128K) A_perm bf16; [128K,+2K) rowsum

using short8  = __attribute__((ext_vector_type(8))) short;
using float4v = __attribute__((ext_vector_type(4))) float;

static __device__ __forceinline__ unsigned int pack_bf16(float lo, float hi) {
    unsigned int ul = __builtin_bit_cast(unsigned int, lo);
    unsigned int uh = __builtin_bit_cast(unsigned int, hi);
    ul = (ul + 0x7FFFu + ((ul >> 16) & 1u)) >> 16;
    uh = (uh + 0x7FFFu + ((uh >> 16) & 1u)) & 0xFFFF0000u;
    return ul | uh;
}
static __device__ __forceinline__ float bf16val(float f) {
    unsigned int u = __builtin_bit_cast(unsigned int, f);
    u = (u + 0x7FFFu + ((u >> 16) & 1u)) & 0xFFFF0000u;
    return __builtin_bit_cast(float, u);
}

// prep: b<32  -> A_perm: fragment-linear bf16 A. Chunk c = k/32 occupies
//                shorts [c*512, +512); lane l holds A[l&15][c*32+(l>>4)*8..+8].
//       32-63 -> per-(m,group) row sums of bf16(A).
__global__ __launch_bounds__(256) void prep_kernel(
    const float* __restrict__ A, unsigned short* __restrict__ wsA,
    float* __restrict__ rowsum)
{
    const int b = blockIdx.x, t = threadIdx.x;
    if (b < 32) {
        const int tid = b * 256 + t;          // 0..8191 = (chunk c)*64 + lane
        const int c = tid >> 6, l = tid & 63;
        const float* src = A + (size_t)(l & 15) * KK + c * 32 + (l >> 4) * 8;
        float4v x0 = *(const float4v*)src;
        float4v x1 = *(const float4v*)(src + 4);
        union { short8 s8; unsigned int u[4]; } p;
        p.u[0] = pack_bf16(x0[0], x0[1]);
        p.u[1] = pack_bf16(x0[2], x0[3]);
        p.u[2] = pack_bf16(x1[0], x1[1]);
        p.u[3] = pack_bf16(x1[2], x1[3]);
        *(short8*)(wsA + (size_t)tid * 8) = p.s8;
    } else {
        const int sid = (b - 32) * 16 + (t >> 4);   // m*32+g
        const int m = sid >> 5, g = sid & 31, j = t & 15;
        const float* p = A + (size_t)m * KK + g * 128 + j * 8;
        float4v x0 = *(const float4v*)p;
        float4v x1 = *(const float4v*)(p + 4);
        float sum = bf16val(x0[0]) + bf16val(x0[1]) + bf16val(x0[2]) + bf16val(x0[3])
                  + bf16val(x1[0]) + bf16val(x1[1]) + bf16val(x1[2]) + bf16val(x1[3]);
        sum += __shfl_xor(sum, 1, 16);
        sum += __shfl_xor(sum, 2, 16);
        sum += __shfl_xor(sum, 4, 16);
        sum += __shfl_xor(sum, 8, 16);
        if (j == 0) rowsum[sid] = sum;
    }
}

// R10 hot kernel: 688 blocks x 256 threads (4 waves). One 16-col n-tile,
// full K per block; wave w owns groups w*8..w*8+7, software-pipelined
// depth-2 (8 qweight int4 + 8 A short8 live -> ~100 VGPR, no spill under
// the 128 cap). All 688 blocks co-resident (~5 blocks/CU capacity at 4
// waves/EU) -> zero tail, continuous load issue, BW-floor shaped.
// Single barrier (R7); epilogue folds bias - sum_g s*(128+z)*rowsum (R9).
__global__ __launch_bounds__(256, 4) void qgemm_kernel(
    const int*            __restrict__ qweight,  // (11008, 2048) words
    const float*          __restrict__ scales,   // (11008, 32)
    const float*          __restrict__ zeros,    // (11008, 32)
    const float*          __restrict__ bias,     // (11008)
    const unsigned short* __restrict__ aperm,    // fragment-linear bf16 A
    const float*          __restrict__ rowsum,   // (16, 32)
    float*                __restrict__ out)      // (16, 11008) fp32
{
    __shared__ float red[4][16][16];   // per-wave partials (4 KB)
    __shared__ float szs[32][17];      // s*(128+z), stride 17 (conflict-free)
    __shared__ float rss[16][33];      // rowsum, padded

    const int t = threadIdx.x;
    const int n0 = blockIdx.x * 16;
    const int wid = t >> 6, lane = t & 63;
    const int nl = lane & 15, quad = lane >> 4;
    const int n = n0 + nl;
    const int g0 = wid * 8;                       // first of this wave's 8 groups

    const int* qrow = qweight + (size_t)n * KW + g0 * 64 + quad * 4;
    const unsigned short* ap = aperm + (size_t)g0 * 2048 + (size_t)lane * 8;
    const float* srow = scales + (size_t)n * NGRP + g0;

    // group J load: 4x int4 qweight (64 consecutive words/row), 4x short8 A frag
#define LOADG(J, QW, AV, SS)                                                  \
    {                                                                         \
        _Pragma("unroll")                                                     \
        for (int c = 0; c < 4; ++c) {                                         \
            QW[c] = *(const int4*)(qrow + (J) * 64 + c * 16);                 \
            AV[c] = *(const short8*)(ap + (J) * 2048 + c * 512);              \
        }                                                                     \
        SS = srow[(J)];                                                       \
    }

#define COMP(QW, AV, SS)                                                      \
    {                                                                         \
        float4v accg = {0.f, 0.f, 0.f, 0.f};                                  \
        _Pragma("unroll")                                                     \
        for (int c = 0; c < 4; ++c) {                                         \
            const unsigned int x0 = (unsigned int)QW[c].x;                    \
            const unsigned int x1 = (unsigned int)QW[c].y;                    \
            const unsigned int x2 = (unsigned int)QW[c].z;                    \
            const unsigned int x3 = (unsigned int)QW[c].w;                    \
            union { short8 s8; unsigned int u[4]; } bf;  /* bf16(128+q) */    \
            bf.u[0] = (x0 & 0xFu) | ((x0 << 12) & 0x000F0000u) | 0x43004300u; \
            bf.u[1] = (x1 & 0xFu) | ((x1 << 12) & 0x000F0000u) | 0x43004300u; \
            bf.u[2] = (x2 & 0xFu) | ((x2 << 12) & 0x000F0000u) | 0x43004300u; \
            bf.u[3] = (x3 & 0xFu) | ((x3 << 12) & 0x000F0000u) | 0x43004300u; \
            accg = __builtin_amdgcn_mfma_f32_16x16x32_bf16(AV[c], bf.s8,      \
                                                           accg, 0, 0, 0);    \
        }                                                                     \
        _Pragma("unroll")                                                     \
        for (int r = 0; r < 4; ++r) tot[r] += (SS) * accg[r];                 \
    }

    int4   qwA[4], qwB[4];
    short8 aA[4],  aB[4];
    float  sA, sB;
    float4v tot = {0.f, 0.f, 0.f, 0.f};

    // prime the pipe: groups g0, g0+1 in flight before anything else
    LOADG(0, qwA, aA, sA)
    LOADG(1, qwB, aB, sB)

    // epilogue staging (512 entries each, 2 per thread; consumed after barrier)
    {
        const int sg = t & 31, sn = t >> 5;        // sn = 0..7
        szs[sg][sn]     = scales[(size_t)(n0 + sn) * NGRP + sg]
                        * (128.0f + zeros[(size_t)(n0 + sn) * NGRP + sg]);
        szs[sg][sn + 8] = scales[(size_t)(n0 + sn + 8) * NGRP + sg]
                        * (128.0f + zeros[(size_t)(n0 + sn + 8) * NGRP + sg]);
        rss[sn][sg]      = rowsum[t];
        rss[sn + 8][sg]  = rowsum[t + 256];
    }

    // steady state: compute group j (buf parity), refill same buf with j+2
    COMP(qwA, aA, sA)  LOADG(2, qwA, aA, sA)
    COMP(qwB, aB, sB)  LOADG(3, qwB, aB, sB)
    COMP(qwA, aA, sA)  LOADG(4, qwA, aA, sA)
    COMP(qwB, aB, sB)  LOADG(5, qwB, aB, sB)
    COMP(qwA, aA, sA)  LOADG(6, qwA, aA, sA)
    COMP(qwB, aB, sB)  LOADG(7, qwB, aB, sB)
    COMP(qwA, aA, sA)
    COMP(qwB, aB, sB)
#undef LOADG
#undef COMP

    // C/D mapping: m = quad*4+r, n = nl  [m89]
    #pragma unroll
    for (int r = 0; r < 4; ++r)
        red[wid][quad * 4 + r][nl] = tot[r];
    __syncthreads();   // the ONLY barrier

    {
        const int m = t >> 4, nn = t & 15;         // 256 threads = 16x16 outputs
        float v = red[0][m][nn] + red[1][m][nn] + red[2][m][nn] + red[3][m][nn];
        float corr = 0.f;
        #pragma unroll
        for (int g = 0; g < 32; ++g)
            corr = __builtin_fmaf(szs[g][nn], rss[m][g], corr);
        out[(size_t)m * NN + n0 + nn] = bias[n0 + nn] + v - corr;
    }
}

extern "C" void kernel_launch(void* const* d_in, const int* in_sizes, int n_in,
                              void* d_out, int out_size, void* d_ws, size_t ws_size,
                              hipStream_t stream) {
    const float* A       = (const float*)d_in[0];
    const int*   qweight = (const int*)d_in[1];
    const float* scales  = (const float*)d_in[2];
    const float* zeros   = (const float*)d_in[3];
    const float* bias    = (const float*)d_in[4];
    float*       out     = (float*)d_out;

    unsigned short* wsA = (unsigned short*)d_ws;
    float* rowsum       = (float*)((char*)d_ws + WS_RS_OFF);

    prep_kernel<<<dim3(64), dim3(256), 0, stream>>>(A, wsA, rowsum);
    qgemm_kernel<<<dim3(688), dim3(256), 0, stream>>>(qweight, scales, zeros, bias,
                                                      wsA, rowsum, out);
}